// Round 9
// baseline (196.656 us; speedup 1.0000x reference)
//
#include <hip/hip_runtime.h>
#include <math.h>

#define NB 10
#define NCLS 100

// R2 (champion, 107.7us) with finalize fused via last-block-done counter.
// Thread-per-row: 25 float4 loads issued up-front (400B in flight/thread,
// no barriers in the hot path) -> max, sum-of-exp, p = softmax[target].
// corr = (row[t] == max) (exact fp32 ties measure-zero; validated R2-R8).
// fp32 LDS partials -> double global atomics (device-scope) -> last block
// computes ECE in fp64, reading gacc with atomicAdd(p,0.0) for cross-XCD
// coherence. absmax 0.0 in all 8 prior rounds with this arithmetic.
__global__ __launch_bounds__(256) void ece_main(const float* __restrict__ outputs,
                                                const int* __restrict__ targets,
                                                double* __restrict__ gacc,
                                                unsigned int* __restrict__ done,
                                                float* __restrict__ out,
                                                int nrows) {
    __shared__ float s_cnt[NB], s_sp[NB], s_sc[NB];
    const int tid = threadIdx.x;
    if (tid < NB) { s_cnt[tid] = 0.f; s_sp[tid] = 0.f; s_sc[tid] = 0.f; }
    __syncthreads();

    const int gtid   = blockIdx.x * blockDim.x + tid;
    const int stride = gridDim.x * blockDim.x;

    for (int r = gtid; r < nrows; r += stride) {
        const float* __restrict__ row = outputs + (size_t)r * NCLS;

        const int t = targets[r];          // coalesced 4B
        float x[NCLS];
        #pragma unroll
        for (int j = 0; j < NCLS / 4; ++j) {
            *reinterpret_cast<float4*>(&x[4 * j]) =
                *reinterpret_cast<const float4*>(row + 4 * j);
        }
        const float tv = row[t];           // scalar, L1-hot (row just fetched)

        // row max: 4 independent chains for ILP, then combine
        float m0 = x[0], m1 = x[1], m2 = x[2], m3 = x[3];
        #pragma unroll
        for (int j = 4; j < NCLS; j += 4) {
            m0 = fmaxf(m0, x[j]);
            m1 = fmaxf(m1, x[j + 1]);
            m2 = fmaxf(m2, x[j + 2]);
            m3 = fmaxf(m3, x[j + 3]);
        }
        const float m = fmaxf(fmaxf(m0, m1), fmaxf(m2, m3));

        // sum of exp(x - m), 4 accumulators
        float a0 = 0.f, a1 = 0.f, a2 = 0.f, a3 = 0.f;
        #pragma unroll
        for (int j = 0; j < NCLS; j += 4) {
            a0 += __expf(x[j] - m);
            a1 += __expf(x[j + 1] - m);
            a2 += __expf(x[j + 2] - m);
            a3 += __expf(x[j + 3] - m);
        }
        const float s  = (a0 + a1) + (a2 + a3);
        const float te = __expf(tv - m);
        const float p  = te / s;                       // in (0, 1]
        const float corr = (tv == m) ? 1.0f : 0.0f;    // pred==target

        // bin = (#boundaries strictly < p) - 1 ; p==0 -> excluded
        const float b[NB + 1] = {0.0f, 0.1f, 0.2f, 0.3f, 0.4f, 0.5f,
                                 0.6f, 0.7f, 0.8f, 0.9f, 1.0f};
        int j = 0;
        #pragma unroll
        for (int k = 0; k <= NB; ++k) j += (b[k] < p) ? 1 : 0;
        int bin = j - 1;
        if (bin >= 0) {
            if (bin > NB - 1) bin = NB - 1;
            atomicAdd(&s_cnt[bin], 1.0f);
            atomicAdd(&s_sp[bin], p);
            atomicAdd(&s_sc[bin], corr);
        }
    }

    __syncthreads();
    if (tid < NB) {
        atomicAdd(&gacc[tid],          (double)s_cnt[tid]);
        atomicAdd(&gacc[NB + tid],     (double)s_sp[tid]);
        atomicAdd(&gacc[2 * NB + tid], (double)s_sc[tid]);
    }
    __syncthreads();

    // last block finalizes (fused ece_final: saves one kernel launch)
    if (tid == 0) {
        __threadfence();
        const unsigned int old = atomicAdd(done, 1u);
        if (old == gridDim.x - 1) {
            double ece = 0.0, total = 0.0;
            #pragma unroll 1
            for (int i = 0; i < NB; ++i) {
                const double c  = atomicAdd(&gacc[i], 0.0);           // coherent read
                const double sp = atomicAdd(&gacc[NB + i], 0.0);
                const double sc = atomicAdd(&gacc[2 * NB + i], 0.0);
                if (c > 0.0) {
                    ece += c * fabs(sp / c - sc / c);
                    total += c;
                }
            }
            out[0] = (total > 0.0) ? (float)(ece / total) : 0.0f;
        }
    }
}

extern "C" void kernel_launch(void* const* d_in, const int* in_sizes, int n_in,
                              void* d_out, int out_size, void* d_ws, size_t ws_size,
                              hipStream_t stream) {
    const float* outputs = (const float*)d_in[0];
    const int*   targets = (const int*)d_in[1];
    float* out   = (float*)d_out;
    double* gacc = (double*)d_ws;                          // 30 doubles
    unsigned int* done = (unsigned int*)((char*)d_ws + 3 * NB * sizeof(double));

    const int nrows = in_sizes[1];  // 1,000,000

    // zero accumulators + done counter (256B region)
    hipMemsetAsync(d_ws, 0, 256, stream);

    const int blocks = 2048;  // ~1.9 rows/thread grid-stride (champion config)
    ece_main<<<blocks, 256, 0, stream>>>(outputs, targets, gacc, done, out, nrows);
}

// Round 10
// 109.215 us; speedup vs baseline: 1.8006x; 1.8006x over previous
//
#include <hip/hip_runtime.h>
#include <math.h>

#define NB 10
#define NCLS 100

// R2's champion structure (thread-per-row, all 25 float4 loads issued
// up-front, no barriers, grid-stride, separate finalize kernel) with the
// anchor-softmax consumption (validated absmax 0.0 in R5/R8): exp(x-anchor)
// consumes each chunk as it arrives, so no x[100] retention -> VGPR fits in
// 128 -> 4 waves/SIMD (vs R2's 3) at the same 400B/thread in flight.
// __launch_bounds__(256,4) pins the register budget. fp32 LDS partials ->
// double global atomics -> fp64 finalize (absmax 0.0 in R1-R9).
__global__ __launch_bounds__(256, 4) void ece_main(const float* __restrict__ outputs,
                                                   const int* __restrict__ targets,
                                                   double* __restrict__ gacc,
                                                   int nrows) {
    __shared__ float s_cnt[NB], s_sp[NB], s_sc[NB];
    const int tid = threadIdx.x;
    if (tid < NB) { s_cnt[tid] = 0.f; s_sp[tid] = 0.f; s_sc[tid] = 0.f; }
    __syncthreads();

    const int gtid   = blockIdx.x * blockDim.x + tid;
    const int stride = gridDim.x * blockDim.x;

    for (int r = gtid; r < nrows; r += stride) {
        const float4* __restrict__ R =
            reinterpret_cast<const float4*>(outputs + (size_t)r * NCLS);
        const int t  = targets[r];
        const int tq = t >> 2;
        const int tr = t & 3;

        // issue ALL 25 loads up-front (400B in flight, like R2)
        float4 v[25];
        #pragma unroll
        for (int k = 0; k < 25; ++k) v[k] = R[k];

        // consume in arrival order; registers retire as chunks are folded in
        const float anchor = fmaxf(fmaxf(v[0].x, v[0].y), fmaxf(v[0].z, v[0].w));
        float m = anchor;
        float tv = 0.f;
        float s0 = 0.f, s1 = 0.f, s2 = 0.f, s3 = 0.f;
        #pragma unroll
        for (int k = 0; k < 25; ++k) {
            const float4 w = v[k];
            m = fmaxf(m, fmaxf(fmaxf(w.x, w.y), fmaxf(w.z, w.w)));
            if (k == tq)
                tv = (tr == 0) ? w.x : (tr == 1) ? w.y : (tr == 2) ? w.z : w.w;
            s0 += __expf(w.x - anchor);
            s1 += __expf(w.y - anchor);
            s2 += __expf(w.z - anchor);
            s3 += __expf(w.w - anchor);
        }

        const float s  = (s0 + s1) + (s2 + s3);
        const float te = __expf(tv - anchor);
        const float p  = te / s;                      // in (0, ~1]
        const float corr = (tv == m) ? 1.0f : 0.0f;   // ties measure-zero

        // bin = (#boundaries strictly < p) - 1 ; p==0 -> excluded
        const float b[NB + 1] = {0.0f, 0.1f, 0.2f, 0.3f, 0.4f, 0.5f,
                                 0.6f, 0.7f, 0.8f, 0.9f, 1.0f};
        int j = 0;
        #pragma unroll
        for (int k = 0; k <= NB; ++k) j += (b[k] < p) ? 1 : 0;
        int bin = j - 1;
        if (bin >= 0) {
            if (bin > NB - 1) bin = NB - 1;
            atomicAdd(&s_cnt[bin], 1.0f);
            atomicAdd(&s_sp[bin], p);
            atomicAdd(&s_sc[bin], corr);
        }
    }

    __syncthreads();
    if (tid < NB) {
        atomicAdd(&gacc[tid],          (double)s_cnt[tid]);
        atomicAdd(&gacc[NB + tid],     (double)s_sp[tid]);
        atomicAdd(&gacc[2 * NB + tid], (double)s_sc[tid]);
    }
}

__global__ void ece_final(const double* __restrict__ gacc, float* __restrict__ out) {
    if (threadIdx.x == 0 && blockIdx.x == 0) {
        double ece = 0.0, total = 0.0;
        for (int i = 0; i < NB; ++i) {
            const double c = gacc[i];
            if (c > 0.0) {
                const double ap = gacc[NB + i] / c;
                const double ac = gacc[2 * NB + i] / c;
                ece += c * fabs(ap - ac);
                total += c;
            }
        }
        out[0] = (total > 0.0) ? (float)(ece / total) : 0.0f;
    }
}

extern "C" void kernel_launch(void* const* d_in, const int* in_sizes, int n_in,
                              void* d_out, int out_size, void* d_ws, size_t ws_size,
                              hipStream_t stream) {
    const float* outputs = (const float*)d_in[0];
    const int*   targets = (const int*)d_in[1];
    float* out   = (float*)d_out;
    double* gacc = (double*)d_ws;

    const int nrows = in_sizes[1];  // 1,000,000

    hipMemsetAsync(gacc, 0, 3 * NB * sizeof(double), stream);

    const int blocks = 2048;  // champion config: grid-stride, ~1.9 rows/thread
    ece_main<<<blocks, 256, 0, stream>>>(outputs, targets, gacc, nrows);
    ece_final<<<1, 64, 0, stream>>>(gacc, out);
}